// Round 5
// baseline (200.234 us; speedup 1.0000x reference)
//
#include <hip/hip_runtime.h>
#include <hip/hip_bf16.h>

#define BB    32
#define LL    8400
#define NGT   64
#define CCH   1
#define KPT   17
#define NTOPK 13

// f32-element chunk offsets (return order: labels, bboxes, poses, scores, gt_index)
#define OFF_LAB  ((size_t)0)
#define OFF_BOX  ((size_t)268800)
#define OFF_POSE ((size_t)1344000)
#define OFF_SC   ((size_t)15052800)
#define OFF_GI   ((size_t)15321600)

// ---------- helpers (fp contract OFF to match the CPU reference op order) ----------

__device__ __forceinline__ float iou_pair(float gx1, float gy1, float gx2, float gy2,
                                          float px1, float py1, float px2, float py2)
{
#pragma clang fp contract(off)
    float ltx = fmaxf(gx1, px1);
    float lty = fmaxf(gy1, py1);
    float rbx = fminf(gx2, px2);
    float rby = fminf(gy2, py2);
    float w = fmaxf(rbx - ltx, 0.0f);
    float h = fmaxf(rby - lty, 0.0f);
    float inter = w * h;
    float ag = (gx2 - gx1) * (gy2 - gy1);
    float ap = (px2 - px1) * (py2 - py1);
    return inter / (ag + ap - inter + 1e-9f);
}

__device__ __forceinline__ bool in_box(float ax, float ay,
                                       float gx1, float gy1, float gx2, float gy2)
{
#pragma clang fp contract(off)
    float m = fminf(fminf(ax - gx1, ay - gy1), fminf(gx2 - ax, gy2 - ay));
    return m > 1e-9f;
}

__device__ __forceinline__ float pow6(float x)
{
#pragma clang fp contract(off)
    float x2 = x * x;
    return (x2 * x2) * x2;
}

// ---------- K1: per-(b,i) masked metric + exact top-13 -> u32 cell (count + idx-sum<<8) ----------

__global__ __launch_bounds__(256) void topk_kernel(
    const float* __restrict__ pred_scores,
    const float* __restrict__ pred_bboxes,
    const float* __restrict__ anchor_points,
    const int*   __restrict__ gt_labels,
    const float* __restrict__ gt_bboxes,
    const float* __restrict__ pad_gt_mask,
    unsigned*    __restrict__ cells)
{
    __shared__ float vals[LL];
    __shared__ float rv[256];
    __shared__ int   ri[256];

    int b = blockIdx.x >> 6;
    int i = blockIdx.x & 63;
    if (pad_gt_mask[b * NGT + i] == 0.0f) return;   // padded row: topk_mask == 0

    int gbase = (b * NGT + i) * 4;
    float gx1 = gt_bboxes[gbase + 0];
    float gy1 = gt_bboxes[gbase + 1];
    float gx2 = gt_bboxes[gbase + 2];
    float gy2 = gt_bboxes[gbase + 3];
    int lbl = gt_labels[b * NGT + i];
    int tid = threadIdx.x;

    // masked metric = score^1 * iou^6 * is_in_gts
    for (int l = tid; l < LL; l += 256) {
        int pidx = b * LL + l;
        float px1 = pred_bboxes[pidx * 4 + 0];
        float py1 = pred_bboxes[pidx * 4 + 1];
        float px2 = pred_bboxes[pidx * 4 + 2];
        float py2 = pred_bboxes[pidx * 4 + 3];
        float iou = iou_pair(gx1, gy1, gx2, gy2, px1, py1, px2, py2);
        float score = pred_scores[pidx * CCH + lbl];
        float metric = score * pow6(iou);
        float ax = anchor_points[l * 2 + 0];
        float ay = anchor_points[l * 2 + 1];
        vals[l] = in_box(ax, ay, gx1, gy1, gx2, gy2) ? metric : 0.0f;
    }
    __syncthreads();

    // 13 argmax passes; comparator = (value desc, index asc) == lax.top_k tie order
    for (int sel = 0; sel < NTOPK; ++sel) {
        float bv = -1.0f;
        int   bl = LL;
        for (int l = tid; l < LL; l += 256) {
            float v = vals[l];                     // consumed entries are -1.0f
            if (v >= 0.0f && (v > bv || (v == bv && l < bl))) { bv = v; bl = l; }
        }
        rv[tid] = bv;
        ri[tid] = bl;
        __syncthreads();
        for (int s = 128; s > 0; s >>= 1) {
            if (tid < s) {
                float ov = rv[tid + s];
                int   oi = ri[tid + s];
                if (ov > rv[tid] || (ov == rv[tid] && oi < ri[tid])) {
                    rv[tid] = ov;
                    ri[tid] = oi;
                }
            }
            __syncthreads();
        }
        if (tid == 0) {
            int lw = ri[0];
            float v = rv[0];
            if (lw >= 0 && lw < LL) {
                vals[lw] = -1.0f;                  // consume
                bool posw;
                if (v > 0.0f) {
                    posw = true;                   // metric>0 implies in_gts
                } else {
                    float ax = anchor_points[lw * 2 + 0];
                    float ay = anchor_points[lw * 2 + 1];
                    posw = in_box(ax, ay, gx1, gy1, gx2, gy2);
                }
                if (posw)
                    atomicAdd(&cells[b * LL + lw], 1u + ((unsigned)i << 8));
            }
        }
        __syncthreads();
    }
}

// ---------- K2: decode cell -> assigned gt (or -1) + row maxima of metric/iou ----------

__global__ __launch_bounds__(256) void decode_kernel(
    const float* __restrict__ pred_scores,
    const float* __restrict__ pred_bboxes,
    const int*   __restrict__ gt_labels,
    const float* __restrict__ gt_bboxes,
    const unsigned* __restrict__ cells,
    int*      __restrict__ assigned,
    unsigned* __restrict__ rowmax_metric,
    unsigned* __restrict__ rowmax_iou)
{
    __shared__ float gsh[NGT * 4];
    int b = blockIdx.y;
    int tid = threadIdx.x;
    for (int k = tid; k < NGT * 4; k += 256) gsh[k] = gt_bboxes[b * NGT * 4 + k];
    __syncthreads();

    int l = blockIdx.x * 256 + tid;
    if (l >= LL) return;
    int idx = b * LL + l;

    unsigned cell = cells[idx];
    int cnt = (int)(cell & 0xFFu);
    if (cnt == 0) { assigned[idx] = -1; return; }

    float px1 = pred_bboxes[idx * 4 + 0];
    float py1 = pred_bboxes[idx * 4 + 1];
    float px2 = pred_bboxes[idx * 4 + 2];
    float py2 = pred_bboxes[idx * 4 + 3];

    int istar;
    if (cnt == 1) {
        int v = (int)(cell >> 8);
        istar = (v >= 0 && v < NGT) ? v : 0;
    } else {
        // reference substitutes is_max_iou over ALL 64 gts (incl. padded), first-max tie
        float best = -1.0f;
        int bi = 0;
        for (int i = 0; i < NGT; ++i) {
            float iou = iou_pair(gsh[i * 4 + 0], gsh[i * 4 + 1], gsh[i * 4 + 2], gsh[i * 4 + 3],
                                 px1, py1, px2, py2);
            if (iou > best) { best = iou; bi = i; }
        }
        istar = bi;
    }
    assigned[idx] = istar;

    float iou = iou_pair(gsh[istar * 4 + 0], gsh[istar * 4 + 1], gsh[istar * 4 + 2], gsh[istar * 4 + 3],
                         px1, py1, px2, py2);
    int lbl = gt_labels[b * NGT + istar];
    float score = pred_scores[idx * CCH + lbl];
    float met = score * pow6(iou);
    atomicMax(&rowmax_metric[b * NGT + istar], __float_as_uint(met));  // values >= 0
    atomicMax(&rowmax_iou[b * NGT + istar], __float_as_uint(iou));
}

// ---------- K3: labels / bboxes / scores / gt_index (float32 stores) ----------

__global__ __launch_bounds__(256) void write_kernel(
    const float* __restrict__ pred_scores,
    const float* __restrict__ pred_bboxes,
    const int*   __restrict__ gt_labels,
    const float* __restrict__ gt_bboxes,
    const int*      __restrict__ assigned,
    const unsigned* __restrict__ rowmax_metric,
    const unsigned* __restrict__ rowmax_iou,
    const int*   __restrict__ bg_ptr,
    float* __restrict__ out)
{
    __shared__ float gsh[NGT * 4];
    int b = blockIdx.y;
    int tid = threadIdx.x;
    for (int k = tid; k < NGT * 4; k += 256) gsh[k] = gt_bboxes[b * NGT * 4 + k];
    __syncthreads();

    int l = blockIdx.x * 256 + tid;
    if (l >= LL) return;
    int idx = b * LL + l;

    int a = assigned[idx];
    bool pos = a >= 0;
    int agi = pos ? a : 0;                 // argmax of all-zero column == 0
    int bg = *bg_ptr;
    int lbl = pos ? gt_labels[b * NGT + agi] : bg;

    out[OFF_LAB + (size_t)idx] = (float)lbl;
    out[OFF_GI + (size_t)idx]  = (float)(b * NGT + agi);

    float4 box;
    box.x = gsh[agi * 4 + 0];
    box.y = gsh[agi * 4 + 1];
    box.z = gsh[agi * 4 + 2];
    box.w = gsh[agi * 4 + 3];
    reinterpret_cast<float4*>(out + OFF_BOX)[idx] = box;

    float am = 0.0f;
    if (pos) {
        float px1 = pred_bboxes[idx * 4 + 0];
        float py1 = pred_bboxes[idx * 4 + 1];
        float px2 = pred_bboxes[idx * 4 + 2];
        float py2 = pred_bboxes[idx * 4 + 3];
        float iou = iou_pair(box.x, box.y, box.z, box.w, px1, py1, px2, py2);
        float score = pred_scores[idx * CCH + gt_labels[b * NGT + a]];
        float met = score * pow6(iou);
        float mm = __uint_as_float(rowmax_metric[b * NGT + a]);
        float mi = __uint_as_float(rowmax_iou[b * NGT + a]);
        am = met / (mm + 1e-9f) * mi;
    }
    int kc = (bg == 0) ? 1 : 0;            // kept class column (C==1)
    out[OFF_SC + (size_t)idx] = (lbl == kc) ? am : 0.0f;
}

// ---------- K4: poses, fully-coalesced elementwise gather ----------

__global__ __launch_bounds__(256) void pose_kernel(
    const float* __restrict__ gt_poses,
    const int*   __restrict__ assigned,
    float* __restrict__ out_poses)
{
    const int TOT = BB * LL * KPT * 3;     // 13,708,800
    int e = blockIdx.x * 256 + threadIdx.x;
    if (e >= TOT) return;
    int anchor = e / (KPT * 3);            // const-div -> magic mul
    int j = e - anchor * (KPT * 3);
    int b = anchor / LL;
    int a = assigned[anchor];
    int agi = a >= 0 ? a : 0;
    out_poses[e] = gt_poses[(size_t)(b * NGT + agi) * (KPT * 3) + j];
}

// ---------- launch ----------

extern "C" void kernel_launch(void* const* d_in, const int* in_sizes, int n_in,
                              void* d_out, int out_size, void* d_ws, size_t ws_size,
                              hipStream_t stream)
{
    const float* pred_scores   = (const float*)d_in[0];
    const float* pred_bboxes   = (const float*)d_in[1];
    // d_in[2] = pred_poses: unused by the reference computation
    const float* anchor_points = (const float*)d_in[3];
    const int*   gt_labels     = (const int*)d_in[4];
    const float* gt_bboxes     = (const float*)d_in[5];
    const float* gt_poses      = (const float*)d_in[6];
    const float* pad_gt_mask   = (const float*)d_in[7];
    const int*   bg_ptr        = (const int*)d_in[8];

    char* ws = (char*)d_ws;
    unsigned* cells         = (unsigned*)ws;                 // 1,075,200 B
    unsigned* rowmax_metric = (unsigned*)(ws + 1075200);     // 8,192 B
    unsigned* rowmax_iou    = (unsigned*)(ws + 1083392);     // 8,192 B
    int*      assigned      = (int*)(ws + 1091584);          // 1,075,200 B
    // total ws use: 2,166,784 B

    hipMemsetAsync(d_ws, 0, 1091584, stream);   // zero cells + rowmax arrays

    topk_kernel<<<BB * NGT, 256, 0, stream>>>(
        pred_scores, pred_bboxes, anchor_points, gt_labels, gt_bboxes, pad_gt_mask, cells);

    dim3 gridBL((LL + 255) / 256, BB);
    decode_kernel<<<gridBL, 256, 0, stream>>>(
        pred_scores, pred_bboxes, gt_labels, gt_bboxes, cells,
        assigned, rowmax_metric, rowmax_iou);

    write_kernel<<<gridBL, 256, 0, stream>>>(
        pred_scores, pred_bboxes, gt_labels, gt_bboxes,
        assigned, rowmax_metric, rowmax_iou, bg_ptr, (float*)d_out);

    const int TOT = BB * LL * KPT * 3;
    pose_kernel<<<(TOT + 255) / 256, 256, 0, stream>>>(
        gt_poses, assigned, (float*)d_out + OFF_POSE);
}

// Round 6
// 134.457 us; speedup vs baseline: 1.4892x; 1.4892x over previous
//
#include <hip/hip_runtime.h>
#include <hip/hip_bf16.h>

#define BB    32
#define LL    8400
#define NGT   64
#define CCH   1
#define KPT   17
#define NTOPK 13

// f32-element chunk offsets (return order: labels, bboxes, poses, scores, gt_index)
#define OFF_LAB  ((size_t)0)
#define OFF_BOX  ((size_t)268800)
#define OFF_POSE ((size_t)1344000)
#define OFF_SC   ((size_t)15052800)
#define OFF_GI   ((size_t)15321600)

// ---------- helpers (fp contract OFF to match the CPU reference op order) ----------

__device__ __forceinline__ float iou_pair(float gx1, float gy1, float gx2, float gy2,
                                          float px1, float py1, float px2, float py2)
{
#pragma clang fp contract(off)
    float ltx = fmaxf(gx1, px1);
    float lty = fmaxf(gy1, py1);
    float rbx = fminf(gx2, px2);
    float rby = fminf(gy2, py2);
    float w = fmaxf(rbx - ltx, 0.0f);
    float h = fmaxf(rby - lty, 0.0f);
    float inter = w * h;
    float ag = (gx2 - gx1) * (gy2 - gy1);
    float ap = (px2 - px1) * (py2 - py1);
    return inter / (ag + ap - inter + 1e-9f);
}

__device__ __forceinline__ bool in_box(float ax, float ay,
                                       float gx1, float gy1, float gx2, float gy2)
{
#pragma clang fp contract(off)
    float m = fminf(fminf(ax - gx1, ay - gy1), fminf(gx2 - ax, gy2 - ay));
    return m > 1e-9f;
}

__device__ __forceinline__ float pow6(float x)
{
#pragma clang fp contract(off)
    float x2 = x * x;
    return (x2 * x2) * x2;
}

// ---------- K1: per-(b,i) single-pass register top-13 + LDS log-merge ----------
// key = (value_bits << 32) | (0xFFFFFFFF - l)  -> order = (value desc, index asc),
// exactly lax.top_k's tie semantics. All metrics >= 0 so float bits are monotone.

__global__ __launch_bounds__(256) void topk_kernel(
    const float* __restrict__ pred_scores,
    const float* __restrict__ pred_bboxes,
    const float* __restrict__ anchor_points,
    const int*   __restrict__ gt_labels,
    const float* __restrict__ gt_bboxes,
    const float* __restrict__ pad_gt_mask,
    unsigned*    __restrict__ cells)
{
    __shared__ unsigned long long lists[256 * NTOPK];   // 26,624 B

    int b = blockIdx.x >> 6;
    int i = blockIdx.x & 63;
    if (pad_gt_mask[b * NGT + i] == 0.0f) return;   // padded row: topk_mask == 0

    int gbase = (b * NGT + i) * 4;
    float gx1 = gt_bboxes[gbase + 0];
    float gy1 = gt_bboxes[gbase + 1];
    float gx2 = gt_bboxes[gbase + 2];
    float gy2 = gt_bboxes[gbase + 3];
    int lbl = gt_labels[b * NGT + i];
    int tid = threadIdx.x;

    // phase 1: single pass, per-thread sorted top-13 in registers (static indices only)
    unsigned long long top[NTOPK];
#pragma unroll
    for (int k = 0; k < NTOPK; ++k) top[k] = 0ull;

    for (int l = tid; l < LL; l += 256) {
        int pidx = b * LL + l;
        float4 pb = reinterpret_cast<const float4*>(pred_bboxes)[pidx];
        float iou = iou_pair(gx1, gy1, gx2, gy2, pb.x, pb.y, pb.z, pb.w);
        float score = pred_scores[pidx * CCH + lbl];
        float metric = score * pow6(iou);
        float2 ap = reinterpret_cast<const float2*>(anchor_points)[l];
        float v = in_box(ap.x, ap.y, gx1, gy1, gx2, gy2) ? metric : 0.0f;
        unsigned long long key =
            ((unsigned long long)__float_as_uint(v) << 32) |
            (unsigned long long)(0xFFFFFFFFu - (unsigned)l);
        if (key > top[NTOPK - 1]) {            // rare after warm-up
#pragma unroll
            for (int k = 0; k < NTOPK; ++k) {  // compare-exchange insertion, static idx
                unsigned long long mx = top[k] > key ? top[k] : key;
                unsigned long long mn = top[k] > key ? key : top[k];
                top[k] = mx;
                key = mn;
            }
        }
    }

#pragma unroll
    for (int k = 0; k < NTOPK; ++k) lists[tid * NTOPK + k] = top[k];
    __syncthreads();

    // phase 2: pairwise merge of sorted desc lists, 8 levels, 1 barrier each
    for (int s = 128; s >= 1; s >>= 1) {
        if (tid < s) {
            int ab = tid * NTOPK;
            int bb = (tid + s) * NTOPK;
            unsigned long long out[NTOPK];
            int ia = 0, ib = 0;                // dynamic indices only on LDS reads
#pragma unroll
            for (int k = 0; k < NTOPK; ++k) {
                unsigned long long ka = lists[ab + ia];   // ia,ib <= k < 13: in-bounds
                unsigned long long kb = lists[bb + ib];
                if (ka >= kb) { out[k] = ka; ++ia; }
                else          { out[k] = kb; ++ib; }
            }
#pragma unroll
            for (int k = 0; k < NTOPK; ++k) lists[ab + k] = out[k];
        }
        __syncthreads();
    }

    // phase 3: emit the 13 winners
    if (tid == 0) {
#pragma unroll
        for (int k = 0; k < NTOPK; ++k) {
            unsigned long long key = lists[k];
            unsigned lw = 0xFFFFFFFFu - (unsigned)(key & 0xFFFFFFFFull);
            float v = __uint_as_float((unsigned)(key >> 32));
            bool posw;
            if (v > 0.0f) {
                posw = true;                   // metric>0 implies in_gts
            } else {
                float2 ap = reinterpret_cast<const float2*>(anchor_points)[lw];
                posw = in_box(ap.x, ap.y, gx1, gy1, gx2, gy2);
            }
            if (posw)
                atomicAdd(&cells[b * LL + lw], 1u + ((unsigned)i << 8));
        }
    }
}

// ---------- K2: decode cell -> assigned gt (or -1) + row maxima of metric/iou ----------

__global__ __launch_bounds__(256) void decode_kernel(
    const float* __restrict__ pred_scores,
    const float* __restrict__ pred_bboxes,
    const int*   __restrict__ gt_labels,
    const float* __restrict__ gt_bboxes,
    const unsigned* __restrict__ cells,
    int*      __restrict__ assigned,
    unsigned* __restrict__ rowmax_metric,
    unsigned* __restrict__ rowmax_iou)
{
    __shared__ float gsh[NGT * 4];
    int b = blockIdx.y;
    int tid = threadIdx.x;
    for (int k = tid; k < NGT * 4; k += 256) gsh[k] = gt_bboxes[b * NGT * 4 + k];
    __syncthreads();

    int l = blockIdx.x * 256 + tid;
    if (l >= LL) return;
    int idx = b * LL + l;

    unsigned cell = cells[idx];
    int cnt = (int)(cell & 0xFFu);
    if (cnt == 0) { assigned[idx] = -1; return; }

    float px1 = pred_bboxes[idx * 4 + 0];
    float py1 = pred_bboxes[idx * 4 + 1];
    float px2 = pred_bboxes[idx * 4 + 2];
    float py2 = pred_bboxes[idx * 4 + 3];

    int istar;
    if (cnt == 1) {
        int v = (int)(cell >> 8);
        istar = (v >= 0 && v < NGT) ? v : 0;
    } else {
        // reference substitutes is_max_iou over ALL 64 gts (incl. padded), first-max tie
        float best = -1.0f;
        int bi = 0;
        for (int i = 0; i < NGT; ++i) {
            float iou = iou_pair(gsh[i * 4 + 0], gsh[i * 4 + 1], gsh[i * 4 + 2], gsh[i * 4 + 3],
                                 px1, py1, px2, py2);
            if (iou > best) { best = iou; bi = i; }
        }
        istar = bi;
    }
    assigned[idx] = istar;

    float iou = iou_pair(gsh[istar * 4 + 0], gsh[istar * 4 + 1], gsh[istar * 4 + 2], gsh[istar * 4 + 3],
                         px1, py1, px2, py2);
    int lbl = gt_labels[b * NGT + istar];
    float score = pred_scores[idx * CCH + lbl];
    float met = score * pow6(iou);
    atomicMax(&rowmax_metric[b * NGT + istar], __float_as_uint(met));  // values >= 0
    atomicMax(&rowmax_iou[b * NGT + istar], __float_as_uint(iou));
}

// ---------- K3: labels / bboxes / scores / gt_index (float32 stores) ----------

__global__ __launch_bounds__(256) void write_kernel(
    const float* __restrict__ pred_scores,
    const float* __restrict__ pred_bboxes,
    const int*   __restrict__ gt_labels,
    const float* __restrict__ gt_bboxes,
    const int*      __restrict__ assigned,
    const unsigned* __restrict__ rowmax_metric,
    const unsigned* __restrict__ rowmax_iou,
    const int*   __restrict__ bg_ptr,
    float* __restrict__ out)
{
    __shared__ float gsh[NGT * 4];
    int b = blockIdx.y;
    int tid = threadIdx.x;
    for (int k = tid; k < NGT * 4; k += 256) gsh[k] = gt_bboxes[b * NGT * 4 + k];
    __syncthreads();

    int l = blockIdx.x * 256 + tid;
    if (l >= LL) return;
    int idx = b * LL + l;

    int a = assigned[idx];
    bool pos = a >= 0;
    int agi = pos ? a : 0;                 // argmax of all-zero column == 0
    int bg = *bg_ptr;
    int lbl = pos ? gt_labels[b * NGT + agi] : bg;

    out[OFF_LAB + (size_t)idx] = (float)lbl;
    out[OFF_GI + (size_t)idx]  = (float)(b * NGT + agi);

    float4 box;
    box.x = gsh[agi * 4 + 0];
    box.y = gsh[agi * 4 + 1];
    box.z = gsh[agi * 4 + 2];
    box.w = gsh[agi * 4 + 3];
    reinterpret_cast<float4*>(out + OFF_BOX)[idx] = box;

    float am = 0.0f;
    if (pos) {
        float px1 = pred_bboxes[idx * 4 + 0];
        float py1 = pred_bboxes[idx * 4 + 1];
        float px2 = pred_bboxes[idx * 4 + 2];
        float py2 = pred_bboxes[idx * 4 + 3];
        float iou = iou_pair(box.x, box.y, box.z, box.w, px1, py1, px2, py2);
        float score = pred_scores[idx * CCH + gt_labels[b * NGT + a]];
        float met = score * pow6(iou);
        float mm = __uint_as_float(rowmax_metric[b * NGT + a]);
        float mi = __uint_as_float(rowmax_iou[b * NGT + a]);
        am = met / (mm + 1e-9f) * mi;
    }
    int kc = (bg == 0) ? 1 : 0;            // kept class column (C==1)
    out[OFF_SC + (size_t)idx] = (lbl == kc) ? am : 0.0f;
}

// ---------- K4: poses, fully-coalesced elementwise gather ----------

__global__ __launch_bounds__(256) void pose_kernel(
    const float* __restrict__ gt_poses,
    const int*   __restrict__ assigned,
    float* __restrict__ out_poses)
{
    const int TOT = BB * LL * KPT * 3;     // 13,708,800
    int e = blockIdx.x * 256 + threadIdx.x;
    if (e >= TOT) return;
    int anchor = e / (KPT * 3);            // const-div -> magic mul
    int j = e - anchor * (KPT * 3);
    int b = anchor / LL;
    int a = assigned[anchor];
    int agi = a >= 0 ? a : 0;
    out_poses[e] = gt_poses[(size_t)(b * NGT + agi) * (KPT * 3) + j];
}

// ---------- launch ----------

extern "C" void kernel_launch(void* const* d_in, const int* in_sizes, int n_in,
                              void* d_out, int out_size, void* d_ws, size_t ws_size,
                              hipStream_t stream)
{
    const float* pred_scores   = (const float*)d_in[0];
    const float* pred_bboxes   = (const float*)d_in[1];
    // d_in[2] = pred_poses: unused by the reference computation
    const float* anchor_points = (const float*)d_in[3];
    const int*   gt_labels     = (const int*)d_in[4];
    const float* gt_bboxes     = (const float*)d_in[5];
    const float* gt_poses      = (const float*)d_in[6];
    const float* pad_gt_mask   = (const float*)d_in[7];
    const int*   bg_ptr        = (const int*)d_in[8];

    char* ws = (char*)d_ws;
    unsigned* cells         = (unsigned*)ws;                 // 1,075,200 B
    unsigned* rowmax_metric = (unsigned*)(ws + 1075200);     // 8,192 B
    unsigned* rowmax_iou    = (unsigned*)(ws + 1083392);     // 8,192 B
    int*      assigned      = (int*)(ws + 1091584);          // 1,075,200 B
    // total ws use: 2,166,784 B

    hipMemsetAsync(d_ws, 0, 1091584, stream);   // zero cells + rowmax arrays

    topk_kernel<<<BB * NGT, 256, 0, stream>>>(
        pred_scores, pred_bboxes, anchor_points, gt_labels, gt_bboxes, pad_gt_mask, cells);

    dim3 gridBL((LL + 255) / 256, BB);
    decode_kernel<<<gridBL, 256, 0, stream>>>(
        pred_scores, pred_bboxes, gt_labels, gt_bboxes, cells,
        assigned, rowmax_metric, rowmax_iou);

    write_kernel<<<gridBL, 256, 0, stream>>>(
        pred_scores, pred_bboxes, gt_labels, gt_bboxes,
        assigned, rowmax_metric, rowmax_iou, bg_ptr, (float*)d_out);

    const int TOT = BB * LL * KPT * 3;
    pose_kernel<<<(TOT + 255) / 256, 256, 0, stream>>>(
        gt_poses, assigned, (float*)d_out + OFF_POSE);
}

// Round 7
// 128.328 us; speedup vs baseline: 1.5603x; 1.0478x over previous
//
#include <hip/hip_runtime.h>
#include <hip/hip_bf16.h>

#define BB    32
#define LL    8400
#define NGT   64
#define CCH   1
#define KPT   17
#define NTOPK 13

// f32-element chunk offsets (return order: labels, bboxes, poses, scores, gt_index)
#define OFF_LAB  ((size_t)0)
#define OFF_BOX  ((size_t)268800)
#define OFF_POSE ((size_t)1344000)
#define OFF_SC   ((size_t)15052800)
#define OFF_GI   ((size_t)15321600)

// ---------- helpers (fp contract OFF to match the CPU reference op order) ----------

__device__ __forceinline__ float iou_pair(float gx1, float gy1, float gx2, float gy2,
                                          float px1, float py1, float px2, float py2)
{
#pragma clang fp contract(off)
    float ltx = fmaxf(gx1, px1);
    float lty = fmaxf(gy1, py1);
    float rbx = fminf(gx2, px2);
    float rby = fminf(gy2, py2);
    float w = fmaxf(rbx - ltx, 0.0f);
    float h = fmaxf(rby - lty, 0.0f);
    float inter = w * h;
    float ag = (gx2 - gx1) * (gy2 - gy1);
    float ap = (px2 - px1) * (py2 - py1);
    return inter / (ag + ap - inter + 1e-9f);
}

__device__ __forceinline__ bool in_box(float ax, float ay,
                                       float gx1, float gy1, float gx2, float gy2)
{
#pragma clang fp contract(off)
    float m = fminf(fminf(ax - gx1, ay - gy1), fminf(gx2 - ax, gy2 - ay));
    return m > 1e-9f;
}

__device__ __forceinline__ float pow6(float x)
{
#pragma clang fp contract(off)
    float x2 = x * x;
    return (x2 * x2) * x2;
}

// ---------- K1: per-(b,i) single-pass register top-13 + wave shfl extraction ----------
// key = (value_bits << 32) | (0xFFFFFFFF - l)  -> order = (value desc, index asc),
// exactly lax.top_k's tie semantics. Keys are UNIQUE (index field) -> exactly one
// winning lane per extraction round.

__global__ __launch_bounds__(256) void topk_kernel(
    const float* __restrict__ pred_scores,
    const float* __restrict__ pred_bboxes,
    const float* __restrict__ anchor_points,
    const int*   __restrict__ gt_labels,
    const float* __restrict__ gt_bboxes,
    const float* __restrict__ pad_gt_mask,
    unsigned*    __restrict__ cells)
{
    __shared__ unsigned long long wlists[4 * NTOPK];   // 416 B

    int b = blockIdx.x >> 6;
    int i = blockIdx.x & 63;
    if (pad_gt_mask[b * NGT + i] == 0.0f) return;   // padded row: topk_mask == 0 (uniform)

    int gbase = (b * NGT + i) * 4;
    float gx1 = gt_bboxes[gbase + 0];
    float gy1 = gt_bboxes[gbase + 1];
    float gx2 = gt_bboxes[gbase + 2];
    float gy2 = gt_bboxes[gbase + 3];
    int lbl = gt_labels[b * NGT + i];
    int tid = threadIdx.x;

    // phase 1: single pass, per-thread sorted top-13 in registers (static indices only)
    unsigned long long top[NTOPK];
#pragma unroll
    for (int k = 0; k < NTOPK; ++k) top[k] = 0ull;

#pragma unroll 2
    for (int l = tid; l < LL; l += 256) {
        int pidx = b * LL + l;
        float4 pb = reinterpret_cast<const float4*>(pred_bboxes)[pidx];
        float iou = iou_pair(gx1, gy1, gx2, gy2, pb.x, pb.y, pb.z, pb.w);
        float score = pred_scores[pidx * CCH + lbl];
        float metric = score * pow6(iou);
        float2 ap = reinterpret_cast<const float2*>(anchor_points)[l];
        float v = in_box(ap.x, ap.y, gx1, gy1, gx2, gy2) ? metric : 0.0f;
        unsigned long long key =
            ((unsigned long long)__float_as_uint(v) << 32) |
            (unsigned long long)(0xFFFFFFFFu - (unsigned)l);
        if (key > top[NTOPK - 1]) {
#pragma unroll
            for (int k = 0; k < NTOPK; ++k) {  // compare-exchange insertion, static idx
                unsigned long long mx = top[k] > key ? top[k] : key;
                unsigned long long mn = top[k] > key ? key : top[k];
                top[k] = mx;
                key = mn;
            }
        }
    }

    // phase 2a: per-wave 13-round argmax extraction, barrier-free.
    // Winner lane statically shifts its list; lane 0 streams winners to LDS.
    int wave = tid >> 6;
    int lane = tid & 63;
#pragma unroll
    for (int k = 0; k < NTOPK; ++k) {
        unsigned long long m = top[0];
#pragma unroll
        for (int off = 32; off > 0; off >>= 1) {
            unsigned long long o = __shfl_xor(m, off);
            m = o > m ? o : m;
        }
        if (lane == 0) wlists[wave * NTOPK + k] = m;
        if (top[0] == m) {                     // unique key -> exactly one lane
#pragma unroll
            for (int j = 0; j < NTOPK - 1; ++j) top[j] = top[j + 1];
            top[NTOPK - 1] = 0ull;
        }
    }
    __syncthreads();

    // phase 2b: tid 0 merges the 4 sorted wave lists (dynamic idx only on LDS) + emits
    if (tid == 0) {
        int p0 = 0, p1 = 0, p2 = 0, p3 = 0;
        for (int k = 0; k < NTOPK; ++k) {
            unsigned long long k0 = wlists[0 * NTOPK + p0];
            unsigned long long k1 = wlists[1 * NTOPK + p1];
            unsigned long long k2 = wlists[2 * NTOPK + p2];
            unsigned long long k3 = wlists[3 * NTOPK + p3];
            unsigned long long m01 = k0 >= k1 ? k0 : k1;
            unsigned long long m23 = k2 >= k3 ? k2 : k3;
            unsigned long long m = m01 >= m23 ? m01 : m23;
            if (m == k0)      ++p0;
            else if (m == k1) ++p1;
            else if (m == k2) ++p2;
            else              ++p3;

            unsigned lw = 0xFFFFFFFFu - (unsigned)(m & 0xFFFFFFFFull);
            float v = __uint_as_float((unsigned)(m >> 32));
            bool posw;
            if (v > 0.0f) {
                posw = true;                   // metric>0 implies in_gts
            } else {
                float2 ap = reinterpret_cast<const float2*>(anchor_points)[lw];
                posw = in_box(ap.x, ap.y, gx1, gy1, gx2, gy2);
            }
            if (posw)
                atomicAdd(&cells[b * LL + lw], 1u + ((unsigned)i << 8));
        }
    }
}

// ---------- K2: decode cell -> assigned gt (or -1) + row maxima of metric/iou ----------

__global__ __launch_bounds__(256) void decode_kernel(
    const float* __restrict__ pred_scores,
    const float* __restrict__ pred_bboxes,
    const int*   __restrict__ gt_labels,
    const float* __restrict__ gt_bboxes,
    const unsigned* __restrict__ cells,
    int*      __restrict__ assigned,
    unsigned* __restrict__ rowmax_metric,
    unsigned* __restrict__ rowmax_iou)
{
    __shared__ float gsh[NGT * 4];
    int b = blockIdx.y;
    int tid = threadIdx.x;
    for (int k = tid; k < NGT * 4; k += 256) gsh[k] = gt_bboxes[b * NGT * 4 + k];
    __syncthreads();

    int l = blockIdx.x * 256 + tid;
    if (l >= LL) return;
    int idx = b * LL + l;

    unsigned cell = cells[idx];
    int cnt = (int)(cell & 0xFFu);
    if (cnt == 0) { assigned[idx] = -1; return; }

    float px1 = pred_bboxes[idx * 4 + 0];
    float py1 = pred_bboxes[idx * 4 + 1];
    float px2 = pred_bboxes[idx * 4 + 2];
    float py2 = pred_bboxes[idx * 4 + 3];

    int istar;
    if (cnt == 1) {
        int v = (int)(cell >> 8);
        istar = (v >= 0 && v < NGT) ? v : 0;
    } else {
        // reference substitutes is_max_iou over ALL 64 gts (incl. padded), first-max tie
        float best = -1.0f;
        int bi = 0;
        for (int i = 0; i < NGT; ++i) {
            float iou = iou_pair(gsh[i * 4 + 0], gsh[i * 4 + 1], gsh[i * 4 + 2], gsh[i * 4 + 3],
                                 px1, py1, px2, py2);
            if (iou > best) { best = iou; bi = i; }
        }
        istar = bi;
    }
    assigned[idx] = istar;

    float iou = iou_pair(gsh[istar * 4 + 0], gsh[istar * 4 + 1], gsh[istar * 4 + 2], gsh[istar * 4 + 3],
                         px1, py1, px2, py2);
    int lbl = gt_labels[b * NGT + istar];
    float score = pred_scores[idx * CCH + lbl];
    float met = score * pow6(iou);
    atomicMax(&rowmax_metric[b * NGT + istar], __float_as_uint(met));  // values >= 0
    atomicMax(&rowmax_iou[b * NGT + istar], __float_as_uint(iou));
}

// ---------- K3: labels / bboxes / scores / gt_index (float32 stores) ----------

__global__ __launch_bounds__(256) void write_kernel(
    const float* __restrict__ pred_scores,
    const float* __restrict__ pred_bboxes,
    const int*   __restrict__ gt_labels,
    const float* __restrict__ gt_bboxes,
    const int*      __restrict__ assigned,
    const unsigned* __restrict__ rowmax_metric,
    const unsigned* __restrict__ rowmax_iou,
    const int*   __restrict__ bg_ptr,
    float* __restrict__ out)
{
    __shared__ float gsh[NGT * 4];
    int b = blockIdx.y;
    int tid = threadIdx.x;
    for (int k = tid; k < NGT * 4; k += 256) gsh[k] = gt_bboxes[b * NGT * 4 + k];
    __syncthreads();

    int l = blockIdx.x * 256 + tid;
    if (l >= LL) return;
    int idx = b * LL + l;

    int a = assigned[idx];
    bool pos = a >= 0;
    int agi = pos ? a : 0;                 // argmax of all-zero column == 0
    int bg = *bg_ptr;
    int lbl = pos ? gt_labels[b * NGT + agi] : bg;

    out[OFF_LAB + (size_t)idx] = (float)lbl;
    out[OFF_GI + (size_t)idx]  = (float)(b * NGT + agi);

    float4 box;
    box.x = gsh[agi * 4 + 0];
    box.y = gsh[agi * 4 + 1];
    box.z = gsh[agi * 4 + 2];
    box.w = gsh[agi * 4 + 3];
    reinterpret_cast<float4*>(out + OFF_BOX)[idx] = box;

    float am = 0.0f;
    if (pos) {
        float px1 = pred_bboxes[idx * 4 + 0];
        float py1 = pred_bboxes[idx * 4 + 1];
        float px2 = pred_bboxes[idx * 4 + 2];
        float py2 = pred_bboxes[idx * 4 + 3];
        float iou = iou_pair(box.x, box.y, box.z, box.w, px1, py1, px2, py2);
        float score = pred_scores[idx * CCH + gt_labels[b * NGT + a]];
        float met = score * pow6(iou);
        float mm = __uint_as_float(rowmax_metric[b * NGT + a]);
        float mi = __uint_as_float(rowmax_iou[b * NGT + a]);
        am = met / (mm + 1e-9f) * mi;
    }
    int kc = (bg == 0) ? 1 : 0;            // kept class column (C==1)
    out[OFF_SC + (size_t)idx] = (lbl == kc) ? am : 0.0f;
}

// ---------- K4: poses, fully-coalesced elementwise gather ----------

__global__ __launch_bounds__(256) void pose_kernel(
    const float* __restrict__ gt_poses,
    const int*   __restrict__ assigned,
    float* __restrict__ out_poses)
{
    const int TOT = BB * LL * KPT * 3;     // 13,708,800
    int e = blockIdx.x * 256 + threadIdx.x;
    if (e >= TOT) return;
    int anchor = e / (KPT * 3);            // const-div -> magic mul
    int j = e - anchor * (KPT * 3);
    int b = anchor / LL;
    int a = assigned[anchor];
    int agi = a >= 0 ? a : 0;
    out_poses[e] = gt_poses[(size_t)(b * NGT + agi) * (KPT * 3) + j];
}

// ---------- launch ----------

extern "C" void kernel_launch(void* const* d_in, const int* in_sizes, int n_in,
                              void* d_out, int out_size, void* d_ws, size_t ws_size,
                              hipStream_t stream)
{
    const float* pred_scores   = (const float*)d_in[0];
    const float* pred_bboxes   = (const float*)d_in[1];
    // d_in[2] = pred_poses: unused by the reference computation
    const float* anchor_points = (const float*)d_in[3];
    const int*   gt_labels     = (const int*)d_in[4];
    const float* gt_bboxes     = (const float*)d_in[5];
    const float* gt_poses      = (const float*)d_in[6];
    const float* pad_gt_mask   = (const float*)d_in[7];
    const int*   bg_ptr        = (const int*)d_in[8];

    char* ws = (char*)d_ws;
    unsigned* cells         = (unsigned*)ws;                 // 1,075,200 B
    unsigned* rowmax_metric = (unsigned*)(ws + 1075200);     // 8,192 B
    unsigned* rowmax_iou    = (unsigned*)(ws + 1083392);     // 8,192 B
    int*      assigned      = (int*)(ws + 1091584);          // 1,075,200 B
    // total ws use: 2,166,784 B

    hipMemsetAsync(d_ws, 0, 1091584, stream);   // zero cells + rowmax arrays

    topk_kernel<<<BB * NGT, 256, 0, stream>>>(
        pred_scores, pred_bboxes, anchor_points, gt_labels, gt_bboxes, pad_gt_mask, cells);

    dim3 gridBL((LL + 255) / 256, BB);
    decode_kernel<<<gridBL, 256, 0, stream>>>(
        pred_scores, pred_bboxes, gt_labels, gt_bboxes, cells,
        assigned, rowmax_metric, rowmax_iou);

    write_kernel<<<gridBL, 256, 0, stream>>>(
        pred_scores, pred_bboxes, gt_labels, gt_bboxes,
        assigned, rowmax_metric, rowmax_iou, bg_ptr, (float*)d_out);

    const int TOT = BB * LL * KPT * 3;
    pose_kernel<<<(TOT + 255) / 256, 256, 0, stream>>>(
        gt_poses, assigned, (float*)d_out + OFF_POSE);
}

// Round 8
// 97.731 us; speedup vs baseline: 2.0488x; 1.3131x over previous
//
#include <hip/hip_runtime.h>
#include <hip/hip_bf16.h>

#define BB    32
#define LL    8400
#define NGT   64
#define CCH   1
#define KPT   17
#define NTOPK 13
#define POOL  2048

// f32-element chunk offsets (return order: labels, bboxes, poses, scores, gt_index)
#define OFF_LAB  ((size_t)0)
#define OFF_BOX  ((size_t)268800)
#define OFF_POSE ((size_t)1344000)
#define OFF_SC   ((size_t)15052800)
#define OFF_GI   ((size_t)15321600)

// ---------- helpers (fp contract OFF to match the CPU reference op order) ----------

__device__ __forceinline__ float iou_pair(float gx1, float gy1, float gx2, float gy2,
                                          float px1, float py1, float px2, float py2)
{
#pragma clang fp contract(off)
    float ltx = fmaxf(gx1, px1);
    float lty = fmaxf(gy1, py1);
    float rbx = fminf(gx2, px2);
    float rby = fminf(gy2, py2);
    float w = fmaxf(rbx - ltx, 0.0f);
    float h = fmaxf(rby - lty, 0.0f);
    float inter = w * h;
    float ag = (gx2 - gx1) * (gy2 - gy1);
    float ap = (px2 - px1) * (py2 - py1);
    return inter / (ag + ap - inter + 1e-9f);
}

__device__ __forceinline__ bool in_box(float ax, float ay,
                                       float gx1, float gy1, float gx2, float gy2)
{
#pragma clang fp contract(off)
    float m = fminf(fminf(ax - gx1, ay - gy1), fminf(gx2 - ax, gy2 - ay));
    return m > 1e-9f;
}

__device__ __forceinline__ float pow6(float x)
{
#pragma clang fp contract(off)
    float x2 = x * x;
    return (x2 * x2) * x2;
}

// ---------- K1: candidate-pool exact top-13 ----------
// key = (value_bits << 32) | (0xFFFFFFFF - l)  -> order = (value desc, index asc),
// exactly lax.top_k's tie semantics; keys unique (index field).
// Pool = all anchors with v>0, plus l<26 unconditionally (covers the zero-metric
// fallback picks: <13 positives => the needed lowest-l zero anchors all have l<26).

__global__ __launch_bounds__(256) void topk_kernel(
    const float* __restrict__ pred_scores,
    const float* __restrict__ pred_bboxes,
    const float* __restrict__ anchor_points,
    const int*   __restrict__ gt_labels,
    const float* __restrict__ gt_bboxes,
    const float* __restrict__ pad_gt_mask,
    unsigned*    __restrict__ cells)
{
    __shared__ unsigned long long pool[POOL];          // 16,384 B
    __shared__ unsigned long long wlists[4 * NTOPK];   // 416 B
    __shared__ int cnt;

    int b = blockIdx.x >> 6;
    int i = blockIdx.x & 63;
    if (pad_gt_mask[b * NGT + i] == 0.0f) return;   // padded row: topk_mask == 0 (uniform)

    int tid = threadIdx.x;
    if (tid == 0) cnt = 0;
    __syncthreads();

    int gbase = (b * NGT + i) * 4;
    float gx1 = gt_bboxes[gbase + 0];
    float gy1 = gt_bboxes[gbase + 1];
    float gx2 = gt_bboxes[gbase + 2];
    float gy2 = gt_bboxes[gbase + 3];
    int lbl = gt_labels[b * NGT + i];

    int lane = tid & 63;
    int wave = tid >> 6;
    unsigned long long lmask = (1ull << lane) - 1;

    // pass 1: stateless scan + ballot-compaction of candidates into LDS pool
#pragma unroll 2
    for (int l = tid; l < LL; l += 256) {
        int pidx = b * LL + l;
        float4 pb = reinterpret_cast<const float4*>(pred_bboxes)[pidx];
        float iou = iou_pair(gx1, gy1, gx2, gy2, pb.x, pb.y, pb.z, pb.w);
        float score = pred_scores[pidx * CCH + lbl];
        float metric = score * pow6(iou);
        float2 ap = reinterpret_cast<const float2*>(anchor_points)[l];
        float v = in_box(ap.x, ap.y, gx1, gy1, gx2, gy2) ? metric : 0.0f;

        bool flag = (v > 0.0f) || (l < 2 * NTOPK);
        unsigned long long mask = __ballot(flag);
        if (mask) {
            int base = 0;
            if (lane == 0) base = atomicAdd(&cnt, __popcll(mask));
            base = __shfl(base, 0);
            if (flag) {
                int slot = base + __popcll(mask & lmask);
                if (slot < POOL) {
                    unsigned long long key =
                        ((unsigned long long)__float_as_uint(v) << 32) |
                        (unsigned long long)(0xFFFFFFFFu - (unsigned)l);
                    pool[slot] = key;
                }
            }
        }
    }
    __syncthreads();

    int total = cnt;
    if (total <= POOL) {
        // pass 2: per-wave 13-round argmax extraction over its strided pool share
#pragma unroll
        for (int k = 0; k < NTOPK; ++k) {
            unsigned long long lm = 0;
            int li = -1;
            for (int e = wave * 64 + lane; e < total; e += 256) {
                unsigned long long pv = pool[e];
                if (pv > lm) { lm = pv; li = e; }
            }
            unsigned long long m = lm;
#pragma unroll
            for (int off = 32; off > 0; off >>= 1) {
                unsigned long long o = __shfl_xor(m, off);
                m = o > m ? o : m;
            }
            if (lane == 0) wlists[wave * NTOPK + k] = m;
            if (li >= 0 && lm == m) pool[li] = 0;   // consume (unique key -> one lane)
        }
    } else {
        // overflow fallback (unreachable on this data): threshold-descend rescan
        unsigned long long prev = ~0ull;
        for (int k = 0; k < NTOPK; ++k) {
            unsigned long long lm = 0;
            for (int l = wave * 64 + lane; l < LL; l += 256) {
                int pidx = b * LL + l;
                float4 pb = reinterpret_cast<const float4*>(pred_bboxes)[pidx];
                float iou = iou_pair(gx1, gy1, gx2, gy2, pb.x, pb.y, pb.z, pb.w);
                float score = pred_scores[pidx * CCH + lbl];
                float metric = score * pow6(iou);
                float2 ap = reinterpret_cast<const float2*>(anchor_points)[l];
                float v = in_box(ap.x, ap.y, gx1, gy1, gx2, gy2) ? metric : 0.0f;
                unsigned long long key =
                    ((unsigned long long)__float_as_uint(v) << 32) |
                    (unsigned long long)(0xFFFFFFFFu - (unsigned)l);
                if (key < prev && key > lm) lm = key;
            }
            unsigned long long m = lm;
#pragma unroll
            for (int off = 32; off > 0; off >>= 1) {
                unsigned long long o = __shfl_xor(m, off);
                m = o > m ? o : m;
            }
            if (lane == 0) wlists[wave * NTOPK + k] = m;
            prev = m;
        }
    }
    __syncthreads();

    // pass 3: tid 0 merges the 4 sorted wave lists + emits (proven r5-r7 semantics)
    if (tid == 0) {
        int p0 = 0, p1 = 0, p2 = 0, p3 = 0;
        for (int k = 0; k < NTOPK; ++k) {
            unsigned long long k0 = wlists[0 * NTOPK + p0];
            unsigned long long k1 = wlists[1 * NTOPK + p1];
            unsigned long long k2 = wlists[2 * NTOPK + p2];
            unsigned long long k3 = wlists[3 * NTOPK + p3];
            unsigned long long m01 = k0 >= k1 ? k0 : k1;
            unsigned long long m23 = k2 >= k3 ? k2 : k3;
            unsigned long long m = m01 >= m23 ? m01 : m23;
            if (m == k0)      ++p0;
            else if (m == k1) ++p1;
            else if (m == k2) ++p2;
            else              ++p3;
            if (m == 0ull) continue;           // exhausted (cannot happen: pool >= 26)

            unsigned lw = 0xFFFFFFFFu - (unsigned)(m & 0xFFFFFFFFull);
            float v = __uint_as_float((unsigned)(m >> 32));
            bool posw;
            if (v > 0.0f) {
                posw = true;                   // metric>0 implies in_gts
            } else {
                float2 ap = reinterpret_cast<const float2*>(anchor_points)[lw];
                posw = in_box(ap.x, ap.y, gx1, gy1, gx2, gy2);
            }
            if (posw)
                atomicAdd(&cells[b * LL + lw], 1u + ((unsigned)i << 8));
        }
    }
}

// ---------- K2: decode cell -> assigned gt (or -1) + row maxima of metric/iou ----------

__global__ __launch_bounds__(256) void decode_kernel(
    const float* __restrict__ pred_scores,
    const float* __restrict__ pred_bboxes,
    const int*   __restrict__ gt_labels,
    const float* __restrict__ gt_bboxes,
    const unsigned* __restrict__ cells,
    int*      __restrict__ assigned,
    unsigned* __restrict__ rowmax_metric,
    unsigned* __restrict__ rowmax_iou)
{
    __shared__ float gsh[NGT * 4];
    int b = blockIdx.y;
    int tid = threadIdx.x;
    for (int k = tid; k < NGT * 4; k += 256) gsh[k] = gt_bboxes[b * NGT * 4 + k];
    __syncthreads();

    int l = blockIdx.x * 256 + tid;
    if (l >= LL) return;
    int idx = b * LL + l;

    unsigned cell = cells[idx];
    int cnt = (int)(cell & 0xFFu);
    if (cnt == 0) { assigned[idx] = -1; return; }

    float px1 = pred_bboxes[idx * 4 + 0];
    float py1 = pred_bboxes[idx * 4 + 1];
    float px2 = pred_bboxes[idx * 4 + 2];
    float py2 = pred_bboxes[idx * 4 + 3];

    int istar;
    if (cnt == 1) {
        int v = (int)(cell >> 8);
        istar = (v >= 0 && v < NGT) ? v : 0;
    } else {
        // reference substitutes is_max_iou over ALL 64 gts (incl. padded), first-max tie
        float best = -1.0f;
        int bi = 0;
        for (int i = 0; i < NGT; ++i) {
            float iou = iou_pair(gsh[i * 4 + 0], gsh[i * 4 + 1], gsh[i * 4 + 2], gsh[i * 4 + 3],
                                 px1, py1, px2, py2);
            if (iou > best) { best = iou; bi = i; }
        }
        istar = bi;
    }
    assigned[idx] = istar;

    float iou = iou_pair(gsh[istar * 4 + 0], gsh[istar * 4 + 1], gsh[istar * 4 + 2], gsh[istar * 4 + 3],
                         px1, py1, px2, py2);
    int lbl = gt_labels[b * NGT + istar];
    float score = pred_scores[idx * CCH + lbl];
    float met = score * pow6(iou);
    atomicMax(&rowmax_metric[b * NGT + istar], __float_as_uint(met));  // values >= 0
    atomicMax(&rowmax_iou[b * NGT + istar], __float_as_uint(iou));
}

// ---------- K3: labels / bboxes / scores / gt_index (float32 stores) ----------

__global__ __launch_bounds__(256) void write_kernel(
    const float* __restrict__ pred_scores,
    const float* __restrict__ pred_bboxes,
    const int*   __restrict__ gt_labels,
    const float* __restrict__ gt_bboxes,
    const int*      __restrict__ assigned,
    const unsigned* __restrict__ rowmax_metric,
    const unsigned* __restrict__ rowmax_iou,
    const int*   __restrict__ bg_ptr,
    float* __restrict__ out)
{
    __shared__ float gsh[NGT * 4];
    int b = blockIdx.y;
    int tid = threadIdx.x;
    for (int k = tid; k < NGT * 4; k += 256) gsh[k] = gt_bboxes[b * NGT * 4 + k];
    __syncthreads();

    int l = blockIdx.x * 256 + tid;
    if (l >= LL) return;
    int idx = b * LL + l;

    int a = assigned[idx];
    bool pos = a >= 0;
    int agi = pos ? a : 0;                 // argmax of all-zero column == 0
    int bg = *bg_ptr;
    int lbl = pos ? gt_labels[b * NGT + agi] : bg;

    out[OFF_LAB + (size_t)idx] = (float)lbl;
    out[OFF_GI + (size_t)idx]  = (float)(b * NGT + agi);

    float4 box;
    box.x = gsh[agi * 4 + 0];
    box.y = gsh[agi * 4 + 1];
    box.z = gsh[agi * 4 + 2];
    box.w = gsh[agi * 4 + 3];
    reinterpret_cast<float4*>(out + OFF_BOX)[idx] = box;

    float am = 0.0f;
    if (pos) {
        float px1 = pred_bboxes[idx * 4 + 0];
        float py1 = pred_bboxes[idx * 4 + 1];
        float px2 = pred_bboxes[idx * 4 + 2];
        float py2 = pred_bboxes[idx * 4 + 3];
        float iou = iou_pair(box.x, box.y, box.z, box.w, px1, py1, px2, py2);
        float score = pred_scores[idx * CCH + gt_labels[b * NGT + a]];
        float met = score * pow6(iou);
        float mm = __uint_as_float(rowmax_metric[b * NGT + a]);
        float mi = __uint_as_float(rowmax_iou[b * NGT + a]);
        am = met / (mm + 1e-9f) * mi;
    }
    int kc = (bg == 0) ? 1 : 0;            // kept class column (C==1)
    out[OFF_SC + (size_t)idx] = (lbl == kc) ? am : 0.0f;
}

// ---------- K4: poses, fully-coalesced elementwise gather ----------

__global__ __launch_bounds__(256) void pose_kernel(
    const float* __restrict__ gt_poses,
    const int*   __restrict__ assigned,
    float* __restrict__ out_poses)
{
    const int TOT = BB * LL * KPT * 3;     // 13,708,800
    int e = blockIdx.x * 256 + threadIdx.x;
    if (e >= TOT) return;
    int anchor = e / (KPT * 3);            // const-div -> magic mul
    int j = e - anchor * (KPT * 3);
    int b = anchor / LL;
    int a = assigned[anchor];
    int agi = a >= 0 ? a : 0;
    out_poses[e] = gt_poses[(size_t)(b * NGT + agi) * (KPT * 3) + j];
}

// ---------- launch ----------

extern "C" void kernel_launch(void* const* d_in, const int* in_sizes, int n_in,
                              void* d_out, int out_size, void* d_ws, size_t ws_size,
                              hipStream_t stream)
{
    const float* pred_scores   = (const float*)d_in[0];
    const float* pred_bboxes   = (const float*)d_in[1];
    // d_in[2] = pred_poses: unused by the reference computation
    const float* anchor_points = (const float*)d_in[3];
    const int*   gt_labels     = (const int*)d_in[4];
    const float* gt_bboxes     = (const float*)d_in[5];
    const float* gt_poses      = (const float*)d_in[6];
    const float* pad_gt_mask   = (const float*)d_in[7];
    const int*   bg_ptr        = (const int*)d_in[8];

    char* ws = (char*)d_ws;
    unsigned* cells         = (unsigned*)ws;                 // 1,075,200 B
    unsigned* rowmax_metric = (unsigned*)(ws + 1075200);     // 8,192 B
    unsigned* rowmax_iou    = (unsigned*)(ws + 1083392);     // 8,192 B
    int*      assigned      = (int*)(ws + 1091584);          // 1,075,200 B
    // total ws use: 2,166,784 B

    hipMemsetAsync(d_ws, 0, 1091584, stream);   // zero cells + rowmax arrays

    topk_kernel<<<BB * NGT, 256, 0, stream>>>(
        pred_scores, pred_bboxes, anchor_points, gt_labels, gt_bboxes, pad_gt_mask, cells);

    dim3 gridBL((LL + 255) / 256, BB);
    decode_kernel<<<gridBL, 256, 0, stream>>>(
        pred_scores, pred_bboxes, gt_labels, gt_bboxes, cells,
        assigned, rowmax_metric, rowmax_iou);

    write_kernel<<<gridBL, 256, 0, stream>>>(
        pred_scores, pred_bboxes, gt_labels, gt_bboxes,
        assigned, rowmax_metric, rowmax_iou, bg_ptr, (float*)d_out);

    const int TOT = BB * LL * KPT * 3;
    pose_kernel<<<(TOT + 255) / 256, 256, 0, stream>>>(
        gt_poses, assigned, (float*)d_out + OFF_POSE);
}

// Round 9
// 95.632 us; speedup vs baseline: 2.0938x; 1.0219x over previous
//
#include <hip/hip_runtime.h>
#include <hip/hip_bf16.h>

#define BB    32
#define LL    8400
#define NGT   64
#define CCH   1
#define KPT   17
#define NTOPK 13
#define POOL  2048

// f32-element chunk offsets (return order: labels, bboxes, poses, scores, gt_index)
#define OFF_LAB  ((size_t)0)
#define OFF_BOX  ((size_t)268800)
#define OFF_POSE ((size_t)1344000)
#define OFF_SC   ((size_t)15052800)
#define OFF_GI   ((size_t)15321600)

// ---------- helpers (fp contract OFF to match the CPU reference op order) ----------

__device__ __forceinline__ float iou_pair(float gx1, float gy1, float gx2, float gy2,
                                          float px1, float py1, float px2, float py2)
{
#pragma clang fp contract(off)
    float ltx = fmaxf(gx1, px1);
    float lty = fmaxf(gy1, py1);
    float rbx = fminf(gx2, px2);
    float rby = fminf(gy2, py2);
    float w = fmaxf(rbx - ltx, 0.0f);
    float h = fmaxf(rby - lty, 0.0f);
    float inter = w * h;
    float ag = (gx2 - gx1) * (gy2 - gy1);
    float ap = (px2 - px1) * (py2 - py1);
    return inter / (ag + ap - inter + 1e-9f);
}

__device__ __forceinline__ bool in_box(float ax, float ay,
                                       float gx1, float gy1, float gx2, float gy2)
{
#pragma clang fp contract(off)
    float m = fminf(fminf(ax - gx1, ay - gy1), fminf(gx2 - ax, gy2 - ay));
    return m > 1e-9f;
}

__device__ __forceinline__ float pow6(float x)
{
#pragma clang fp contract(off)
    float x2 = x * x;
    return (x2 * x2) * x2;
}

// ---------- K1: candidate-pool exact top-13 (per-lane direct append) ----------
// key = (value_bits << 32) | (0xFFFFFFFF - l)  -> order = (value desc, index asc),
// exactly lax.top_k's tie semantics; keys unique (index field).
// Pool = all anchors with v>0, plus l<26 unconditionally (covers the zero-metric
// fallback picks: <13 positives => the needed lowest-l zero anchors all have l<26).

__global__ __launch_bounds__(256) void topk_kernel(
    const float* __restrict__ pred_scores,
    const float* __restrict__ pred_bboxes,
    const float* __restrict__ anchor_points,
    const int*   __restrict__ gt_labels,
    const float* __restrict__ gt_bboxes,
    const float* __restrict__ pad_gt_mask,
    unsigned*    __restrict__ cells)
{
    __shared__ unsigned long long pool[POOL];          // 16,384 B
    __shared__ unsigned long long wlists[4 * NTOPK];   // 416 B
    __shared__ int cnt;

    int b = blockIdx.x >> 6;
    int i = blockIdx.x & 63;
    if (pad_gt_mask[b * NGT + i] == 0.0f) return;   // padded row: topk_mask == 0 (uniform)

    int tid = threadIdx.x;
    if (tid == 0) cnt = 0;
    __syncthreads();

    int gbase = (b * NGT + i) * 4;
    float gx1 = gt_bboxes[gbase + 0];
    float gy1 = gt_bboxes[gbase + 1];
    float gx2 = gt_bboxes[gbase + 2];
    float gy2 = gt_bboxes[gbase + 3];
    int lbl = gt_labels[b * NGT + i];

    int lane = tid & 63;
    int wave = tid >> 6;

    // pass 1: stateless scan; rare per-lane direct LDS append (no cross-lane chain)
#pragma unroll 4
    for (int l = tid; l < LL; l += 256) {
        int pidx = b * LL + l;
        float4 pb = reinterpret_cast<const float4*>(pred_bboxes)[pidx];
        float iou = iou_pair(gx1, gy1, gx2, gy2, pb.x, pb.y, pb.z, pb.w);
        float score = pred_scores[pidx * CCH + lbl];
        float metric = score * pow6(iou);
        float2 ap = reinterpret_cast<const float2*>(anchor_points)[l];
        float v = in_box(ap.x, ap.y, gx1, gy1, gx2, gy2) ? metric : 0.0f;

        if ((v > 0.0f) || (l < 2 * NTOPK)) {          // ~0.85 appends per lane TOTAL
            int slot = atomicAdd(&cnt, 1);
            if (slot < POOL) {
                unsigned long long key =
                    ((unsigned long long)__float_as_uint(v) << 32) |
                    (unsigned long long)(0xFFFFFFFFu - (unsigned)l);
                pool[slot] = key;
            }
        }
    }
    __syncthreads();

    int total = cnt;
    if (total <= POOL) {
        // pass 2: per-wave 13-round argmax extraction over its strided pool share
#pragma unroll
        for (int k = 0; k < NTOPK; ++k) {
            unsigned long long lm = 0;
            int li = -1;
            for (int e = wave * 64 + lane; e < total; e += 256) {
                unsigned long long pv = pool[e];
                if (pv > lm) { lm = pv; li = e; }
            }
            unsigned long long m = lm;
#pragma unroll
            for (int off = 32; off > 0; off >>= 1) {
                unsigned long long o = __shfl_xor(m, off);
                m = o > m ? o : m;
            }
            if (lane == 0) wlists[wave * NTOPK + k] = m;
            if (li >= 0 && lm == m) pool[li] = 0;   // consume (unique key -> one lane)
        }
    } else {
        // overflow fallback (unreachable on this data): threshold-descend rescan
        unsigned long long prev = ~0ull;
        for (int k = 0; k < NTOPK; ++k) {
            unsigned long long lm = 0;
            for (int l = wave * 64 + lane; l < LL; l += 256) {
                int pidx = b * LL + l;
                float4 pb = reinterpret_cast<const float4*>(pred_bboxes)[pidx];
                float iou = iou_pair(gx1, gy1, gx2, gy2, pb.x, pb.y, pb.z, pb.w);
                float score = pred_scores[pidx * CCH + lbl];
                float metric = score * pow6(iou);
                float2 ap = reinterpret_cast<const float2*>(anchor_points)[l];
                float v = in_box(ap.x, ap.y, gx1, gy1, gx2, gy2) ? metric : 0.0f;
                unsigned long long key =
                    ((unsigned long long)__float_as_uint(v) << 32) |
                    (unsigned long long)(0xFFFFFFFFu - (unsigned)l);
                if (key < prev && key > lm) lm = key;
            }
            unsigned long long m = lm;
#pragma unroll
            for (int off = 32; off > 0; off >>= 1) {
                unsigned long long o = __shfl_xor(m, off);
                m = o > m ? o : m;
            }
            if (lane == 0) wlists[wave * NTOPK + k] = m;
            prev = m;
        }
    }
    __syncthreads();

    // pass 3: tid 0 merges the 4 sorted wave lists + emits (proven r5-r8 semantics)
    if (tid == 0) {
        int p0 = 0, p1 = 0, p2 = 0, p3 = 0;
        for (int k = 0; k < NTOPK; ++k) {
            unsigned long long k0 = wlists[0 * NTOPK + p0];
            unsigned long long k1 = wlists[1 * NTOPK + p1];
            unsigned long long k2 = wlists[2 * NTOPK + p2];
            unsigned long long k3 = wlists[3 * NTOPK + p3];
            unsigned long long m01 = k0 >= k1 ? k0 : k1;
            unsigned long long m23 = k2 >= k3 ? k2 : k3;
            unsigned long long m = m01 >= m23 ? m01 : m23;
            if (m == k0)      ++p0;
            else if (m == k1) ++p1;
            else if (m == k2) ++p2;
            else              ++p3;
            if (m == 0ull) continue;           // exhausted (cannot happen: pool >= 26)

            unsigned lw = 0xFFFFFFFFu - (unsigned)(m & 0xFFFFFFFFull);
            float v = __uint_as_float((unsigned)(m >> 32));
            bool posw;
            if (v > 0.0f) {
                posw = true;                   // metric>0 implies in_gts
            } else {
                float2 ap = reinterpret_cast<const float2*>(anchor_points)[lw];
                posw = in_box(ap.x, ap.y, gx1, gy1, gx2, gy2);
            }
            if (posw)
                atomicAdd(&cells[b * LL + lw], 1u + ((unsigned)i << 8));
        }
    }
}

// ---------- K2: decode cell -> assigned gt (or -1) + row maxima of metric/iou ----------

__global__ __launch_bounds__(256) void decode_kernel(
    const float* __restrict__ pred_scores,
    const float* __restrict__ pred_bboxes,
    const int*   __restrict__ gt_labels,
    const float* __restrict__ gt_bboxes,
    const unsigned* __restrict__ cells,
    int*      __restrict__ assigned,
    unsigned* __restrict__ rowmax_metric,
    unsigned* __restrict__ rowmax_iou)
{
    __shared__ float gsh[NGT * 4];
    int b = blockIdx.y;
    int tid = threadIdx.x;
    for (int k = tid; k < NGT * 4; k += 256) gsh[k] = gt_bboxes[b * NGT * 4 + k];
    __syncthreads();

    int l = blockIdx.x * 256 + tid;
    if (l >= LL) return;
    int idx = b * LL + l;

    unsigned cell = cells[idx];
    int cnt = (int)(cell & 0xFFu);
    if (cnt == 0) { assigned[idx] = -1; return; }

    float px1 = pred_bboxes[idx * 4 + 0];
    float py1 = pred_bboxes[idx * 4 + 1];
    float px2 = pred_bboxes[idx * 4 + 2];
    float py2 = pred_bboxes[idx * 4 + 3];

    int istar;
    if (cnt == 1) {
        int v = (int)(cell >> 8);
        istar = (v >= 0 && v < NGT) ? v : 0;
    } else {
        // reference substitutes is_max_iou over ALL 64 gts (incl. padded), first-max tie
        float best = -1.0f;
        int bi = 0;
        for (int i = 0; i < NGT; ++i) {
            float iou = iou_pair(gsh[i * 4 + 0], gsh[i * 4 + 1], gsh[i * 4 + 2], gsh[i * 4 + 3],
                                 px1, py1, px2, py2);
            if (iou > best) { best = iou; bi = i; }
        }
        istar = bi;
    }
    assigned[idx] = istar;

    float iou = iou_pair(gsh[istar * 4 + 0], gsh[istar * 4 + 1], gsh[istar * 4 + 2], gsh[istar * 4 + 3],
                         px1, py1, px2, py2);
    int lbl = gt_labels[b * NGT + istar];
    float score = pred_scores[idx * CCH + lbl];
    float met = score * pow6(iou);
    atomicMax(&rowmax_metric[b * NGT + istar], __float_as_uint(met));  // values >= 0
    atomicMax(&rowmax_iou[b * NGT + istar], __float_as_uint(iou));
}

// ---------- K3: labels / bboxes / scores / gt_index (float32 stores) ----------

__global__ __launch_bounds__(256) void write_kernel(
    const float* __restrict__ pred_scores,
    const float* __restrict__ pred_bboxes,
    const int*   __restrict__ gt_labels,
    const float* __restrict__ gt_bboxes,
    const int*      __restrict__ assigned,
    const unsigned* __restrict__ rowmax_metric,
    const unsigned* __restrict__ rowmax_iou,
    const int*   __restrict__ bg_ptr,
    float* __restrict__ out)
{
    __shared__ float gsh[NGT * 4];
    int b = blockIdx.y;
    int tid = threadIdx.x;
    for (int k = tid; k < NGT * 4; k += 256) gsh[k] = gt_bboxes[b * NGT * 4 + k];
    __syncthreads();

    int l = blockIdx.x * 256 + tid;
    if (l >= LL) return;
    int idx = b * LL + l;

    int a = assigned[idx];
    bool pos = a >= 0;
    int agi = pos ? a : 0;                 // argmax of all-zero column == 0
    int bg = *bg_ptr;
    int lbl = pos ? gt_labels[b * NGT + agi] : bg;

    out[OFF_LAB + (size_t)idx] = (float)lbl;
    out[OFF_GI + (size_t)idx]  = (float)(b * NGT + agi);

    float4 box;
    box.x = gsh[agi * 4 + 0];
    box.y = gsh[agi * 4 + 1];
    box.z = gsh[agi * 4 + 2];
    box.w = gsh[agi * 4 + 3];
    reinterpret_cast<float4*>(out + OFF_BOX)[idx] = box;

    float am = 0.0f;
    if (pos) {
        float px1 = pred_bboxes[idx * 4 + 0];
        float py1 = pred_bboxes[idx * 4 + 1];
        float px2 = pred_bboxes[idx * 4 + 2];
        float py2 = pred_bboxes[idx * 4 + 3];
        float iou = iou_pair(box.x, box.y, box.z, box.w, px1, py1, px2, py2);
        float score = pred_scores[idx * CCH + gt_labels[b * NGT + a]];
        float met = score * pow6(iou);
        float mm = __uint_as_float(rowmax_metric[b * NGT + a]);
        float mi = __uint_as_float(rowmax_iou[b * NGT + a]);
        am = met / (mm + 1e-9f) * mi;
    }
    int kc = (bg == 0) ? 1 : 0;            // kept class column (C==1)
    out[OFF_SC + (size_t)idx] = (lbl == kc) ? am : 0.0f;
}

// ---------- K4: poses, fully-coalesced elementwise gather ----------

__global__ __launch_bounds__(256) void pose_kernel(
    const float* __restrict__ gt_poses,
    const int*   __restrict__ assigned,
    float* __restrict__ out_poses)
{
    const int TOT = BB * LL * KPT * 3;     // 13,708,800
    int e = blockIdx.x * 256 + threadIdx.x;
    if (e >= TOT) return;
    int anchor = e / (KPT * 3);            // const-div -> magic mul
    int j = e - anchor * (KPT * 3);
    int b = anchor / LL;
    int a = assigned[anchor];
    int agi = a >= 0 ? a : 0;
    out_poses[e] = gt_poses[(size_t)(b * NGT + agi) * (KPT * 3) + j];
}

// ---------- launch ----------

extern "C" void kernel_launch(void* const* d_in, const int* in_sizes, int n_in,
                              void* d_out, int out_size, void* d_ws, size_t ws_size,
                              hipStream_t stream)
{
    const float* pred_scores   = (const float*)d_in[0];
    const float* pred_bboxes   = (const float*)d_in[1];
    // d_in[2] = pred_poses: unused by the reference computation
    const float* anchor_points = (const float*)d_in[3];
    const int*   gt_labels     = (const int*)d_in[4];
    const float* gt_bboxes     = (const float*)d_in[5];
    const float* gt_poses      = (const float*)d_in[6];
    const float* pad_gt_mask   = (const float*)d_in[7];
    const int*   bg_ptr        = (const int*)d_in[8];

    char* ws = (char*)d_ws;
    unsigned* cells         = (unsigned*)ws;                 // 1,075,200 B
    unsigned* rowmax_metric = (unsigned*)(ws + 1075200);     // 8,192 B
    unsigned* rowmax_iou    = (unsigned*)(ws + 1083392);     // 8,192 B
    int*      assigned      = (int*)(ws + 1091584);          // 1,075,200 B
    // total ws use: 2,166,784 B

    hipMemsetAsync(d_ws, 0, 1091584, stream);   // zero cells + rowmax arrays

    topk_kernel<<<BB * NGT, 256, 0, stream>>>(
        pred_scores, pred_bboxes, anchor_points, gt_labels, gt_bboxes, pad_gt_mask, cells);

    dim3 gridBL((LL + 255) / 256, BB);
    decode_kernel<<<gridBL, 256, 0, stream>>>(
        pred_scores, pred_bboxes, gt_labels, gt_bboxes, cells,
        assigned, rowmax_metric, rowmax_iou);

    write_kernel<<<gridBL, 256, 0, stream>>>(
        pred_scores, pred_bboxes, gt_labels, gt_bboxes,
        assigned, rowmax_metric, rowmax_iou, bg_ptr, (float*)d_out);

    const int TOT = BB * LL * KPT * 3;
    pose_kernel<<<(TOT + 255) / 256, 256, 0, stream>>>(
        gt_poses, assigned, (float*)d_out + OFF_POSE);
}